// Round 7
// baseline (231.809 us; speedup 1.0000x reference)
//
#include <hip/hip_runtime.h>
#include <math.h>

// ---------------------------------------------------------------------------
// GAT 2-layer forward — memset + 6 kernels.
//   memset    : bcursor = 0 (32 KB, PADDED: 1 line / bucket)
//   k_prep    : Wt[64][128] = bf16(W1^T), 16 KB, one small block.
//   k_gemm    : h1b = bf16(x@W1) via MFMA 16x16x32_bf16, 64-row tiles,
//               256 thr (R16 structure; split from bin since R17).
//   k_bin     : bin edges by bucket (dst>>9) into BUCKET-STRIDED staged[]
//               (b*MAXB + atomic pos), LDS-reordered. KC_CHUNK=2048, 256 thr.
//               bcursor padded 128B/bucket (R17).
//   kD_group  : per bucket: local 512-dst hist+scan -> offs[d]/dcnt[d];
//               LDS-position edges -> grouped[] (dst-sorted), coalesced
//               flush. 1024 thr, single-wave scan.
//   k_agg1    : one wave/dst. R18: j-loop re-laid as 8 eslots x 8-ch groups —
//               ONE dwordx4 (16B = 8 bf16 ch) per lane per 8 edges replaces
//               16 serialized 2B gathers (R17 profile: 56.6us, VALUBusy 73%,
//               issue-bound; FETCH 117MB is L2-miss->L3 traffic, not HBM —
//               h1b is 12.8MB). w-phase unchanged (lanes = 16 sub x 4 head,
//               LDS layout [sub*4+h]); src idx via 2 bpermute; acc transposed
//               back to lane=channel via intra-wave LDS float4 round-trip.
//               DEPTH-2 grouped prefetch kept. Fused node2 epilogue.
//   k_agg2    : out[d,:] via single 16B pack gather per edge; self on sub==0.
// R4 lesson: random 4B scatter to >L2 buffer costs 64B/line HBM writes.
// segment_max skipped (exp/sum identical post-normalization). h1 as bf16.
// ---------------------------------------------------------------------------

#define NB 256          // bucket array size
#define BSH 9           // bucket shift (512 dst/bucket)
#define CPAD 32         // bcursor stride in ints (128 B = 1 L2 line)
#define SRC_MASK 0x1FFFF
#define KC_CHUNK 2048
#define KC_PT 8         // edges per thread in bin phase (256 threads)
#define MAXB 9216       // capacity/bucket (mean 8163, sigma ~90 -> +11 sigma)

typedef short v8s __attribute__((ext_vector_type(8)));
typedef float v4f __attribute__((ext_vector_type(4)));

static __device__ __forceinline__ unsigned short f2bf(float f) {
    union { float f; unsigned int u; } v; v.f = f;
    unsigned int r = (v.u + 0x7fffu + ((v.u >> 16) & 1u)) >> 16;
    return (unsigned short)r;
}
static __device__ __forceinline__ float bf2f(unsigned short s) {
    union { unsigned int u; float f; } v; v.u = ((unsigned int)s) << 16;
    return v.f;
}
static __device__ __forceinline__ float lo_bf(unsigned int u) {
    union { unsigned int u; float f; } v; v.u = u << 16;
    return v.f;
}
static __device__ __forceinline__ float hi_bf(unsigned int u) {
    union { unsigned int u; float f; } v; v.u = u & 0xffff0000u;
    return v.f;
}
static __device__ __forceinline__ float lrexp(float raw) {
    return __expf(raw > 0.f ? raw : 0.2f * raw);
}

// ---- prelude: Wt[c][k] = bf16(W[k][c]) ----
__global__ __launch_bounds__(1024) void k_prep(const float* __restrict__ W,
                                               unsigned short* __restrict__ Wt) {
    int t = threadIdx.x;
    for (int i = t; i < 8192; i += 1024) {
        int c = i >> 7, k = i & 127;
        Wt[i] = f2bf(W[k * 64 + c]);
    }
}

// ---- MFMA GEMM: 64 rows x 64 cols, K=128, 4 waves ----
__global__ __launch_bounds__(256, 4) void k_gemm(
        const float* __restrict__ x, const unsigned short* __restrict__ Wt,
        const float* __restrict__ att_s, const float* __restrict__ att_d,
        unsigned short* __restrict__ h1b, float* __restrict__ as1,
        float* __restrict__ ad1, int n) {
    __shared__ __align__(16) char smem[33280];
    const int t = threadIdx.x;
    float* Cs = (float*)(smem + 16384);        // 64 x 64, stride 65
    const int row0 = blockIdx.x * 64;
    const int L = t & 63, wv = t >> 6;

    // B-fragments: issue early (global, L2-broadcast), hide under staging
    v8s bfrag[4][4];
    const v8s* Wtv = (const v8s*)Wt;
    const int bci = ((L & 15) << 4) + (L >> 4);
#pragma unroll
    for (int ct = 0; ct < 4; ++ct)
#pragma unroll
        for (int kb = 0; kb < 4; ++kb)
            bfrag[ct][kb] = Wtv[bci + (ct << 8) + (kb << 2)];

    // stage x tile as bf16, swizzled: byte = r*256 + ((k4*8)^((r&7)<<4))
    for (int i = t; i < 2048; i += 256) {
        int r = i >> 5, k4 = i & 31;
        float4 v = make_float4(0.f, 0.f, 0.f, 0.f);
        if (row0 + r < n) v = ((const float4*)x)[(size_t)(row0 + r) * 32 + k4];
        ushort4 u;
        u.x = f2bf(v.x); u.y = f2bf(v.y); u.z = f2bf(v.z); u.w = f2bf(v.w);
        int byte = r * 256 + ((k4 * 8) ^ ((r & 7) << 4));
        *(ushort4*)(smem + byte) = u;
    }
    __syncthreads();

    v4f acc[4] = {{0.f,0.f,0.f,0.f}, {0.f,0.f,0.f,0.f},
                  {0.f,0.f,0.f,0.f}, {0.f,0.f,0.f,0.f}};
    const int row = (wv << 4) + (L & 15);
#pragma unroll
    for (int kb = 0; kb < 4; ++kb) {
        int byte = row * 256 + (((kb << 6) + ((L >> 4) << 4)) ^ ((row & 7) << 4));
        v8s afrag = *(const v8s*)(smem + byte);
#pragma unroll
        for (int ct = 0; ct < 4; ++ct)
            acc[ct] = __builtin_amdgcn_mfma_f32_16x16x32_bf16(
                afrag, bfrag[ct][kb], acc[ct], 0, 0, 0);
    }
    // C -> LDS (stride 65)
#pragma unroll
    for (int ct = 0; ct < 4; ++ct) {
        int col = (ct << 4) + (L & 15);
        int rbase = (wv << 4) + ((L >> 4) << 2);
#pragma unroll
        for (int q = 0; q < 4; ++q)
            Cs[(rbase + q) * 65 + col] = acc[ct][q];
    }
    __syncthreads();
    // h1b: t -> (row = t>>2, q = t&3): 16 cols, coalesced ushort4 x4
    {
        int row = t >> 2, q = t & 3;
        const float* cp = &Cs[row * 65 + q * 16];
        int r = row0 + row;
        if (r < n) {
            ushort4 u0, u1, u2, u3;
            u0.x = f2bf(cp[0]);  u0.y = f2bf(cp[1]);
            u0.z = f2bf(cp[2]);  u0.w = f2bf(cp[3]);
            u1.x = f2bf(cp[4]);  u1.y = f2bf(cp[5]);
            u1.z = f2bf(cp[6]);  u1.w = f2bf(cp[7]);
            u2.x = f2bf(cp[8]);  u2.y = f2bf(cp[9]);
            u2.z = f2bf(cp[10]); u2.w = f2bf(cp[11]);
            u3.x = f2bf(cp[12]); u3.y = f2bf(cp[13]);
            u3.z = f2bf(cp[14]); u3.w = f2bf(cp[15]);
            ushort4* hp = (ushort4*)h1b + ((size_t)r * 16 + q * 4);
            hp[0] = u0; hp[1] = u1; hp[2] = u2; hp[3] = u3;
        }
    }
    // as1/ad1: t -> (row = t&63, h = t>>6); h wave-uniform -> s_load att
    {
        int row = t & 63, h = t >> 6;
        const float* cp = &Cs[row * 65 + h * 16];
        const float* asp = att_s + (h << 4);
        const float* adp = att_d + (h << 4);
        float ps = 0.f, pd = 0.f;
#pragma unroll
        for (int j = 0; j < 16; ++j) {
            ps += cp[j] * asp[j];
            pd += cp[j] * adp[j];
        }
        int r = row0 + row;
        if (r < n) {
            as1[r * 4 + h] = ps;
            ad1[r * 4 + h] = pd;
        }
    }
}

// ---- edge binning (256 threads, 2048 edges/block) ----
__global__ __launch_bounds__(256) void k_bin(
        const int* __restrict__ esrc, const int* __restrict__ edst,
        int* __restrict__ bcursor, unsigned int* __restrict__ staged,
        int E) {
    __shared__ __align__(16) char smem[14336];
    const int t = threadIdx.x;
    unsigned int* pairs = (unsigned int*)smem;               // 8192 B
    unsigned char* binOf = (unsigned char*)(smem + 8192);    // 2048 B
    int* hh    = (int*)(smem + 10240);
    int* lofs  = (int*)(smem + 11264);
    int* lcur  = (int*)(smem + 12288);
    int* gbase = (int*)(smem + 13312);
    int base = blockIdx.x * KC_CHUNK;
    int cnt = E - base; if (cnt > KC_CHUNK) cnt = KC_CHUNK;
    hh[t] = 0; __syncthreads();
    unsigned int myV[KC_PT]; int myBin[KC_PT];
#pragma unroll
    for (int k = 0; k < KC_PT; ++k) {
        int li = k * 256 + t;
        myBin[k] = -1;
        if (li < cnt) {
            int gi = base + li;
            int s = esrc[gi], d = edst[gi];
            int bin = d >> BSH;
            myV[k] = ((unsigned int)(d & ((1 << BSH) - 1)) << 17) | (unsigned int)s;
            myBin[k] = bin;
            atomicAdd(&hh[bin], 1);
        }
    }
    __syncthreads();
    // single-wave scan over 256 bins (4 bins/lane)
    if (t < 64) {
        int hvv[4];
        *(int4*)hvv = *(const int4*)&hh[t * 4];
        int ex[4]; int p = 0;
#pragma unroll
        for (int q = 0; q < 4; ++q) { ex[q] = p; p += hvv[q]; }
        int lsum = p, sc = p;
#pragma unroll
        for (int m = 1; m < 64; m <<= 1) {
            int u = __shfl_up(sc, m);
            if (t >= m) sc += u;
        }
        int lbase = sc - lsum;
#pragma unroll
        for (int q = 0; q < 4; ++q) {
            int b = t * 4 + q;
            lofs[b] = lbase + ex[q];
            lcur[b] = lbase + ex[q];
            if (hvv[q]) gbase[b] = b * MAXB + atomicAdd(&bcursor[b * CPAD], hvv[q]);
        }
    }
    __syncthreads();
#pragma unroll
    for (int k = 0; k < KC_PT; ++k) {
        if (myBin[k] >= 0) {
            int p = atomicAdd(&lcur[myBin[k]], 1);
            pairs[p] = myV[k];
            binOf[p] = (unsigned char)myBin[k];
        }
    }
    __syncthreads();
    for (int i = t; i < cnt; i += 256) {
        int b = binOf[i];
        staged[gbase[b] + (i - lofs[b])] = pairs[i];
    }
}

// Per bucket: local hist over 512 dst -> scan -> offs[d] (strided) + dcnt[d];
// LDS-position edges dst-sorted -> grouped[] coalesced flush.
__global__ __launch_bounds__(1024) void kD_group(const unsigned int* __restrict__ staged,
                                                 const int* __restrict__ bcursor,
                                                 unsigned int* __restrict__ grouped,
                                                 int* __restrict__ offs,
                                                 int* __restrict__ dcnt, int n) {
    __shared__ int lh[512], lofs2[512], lcur2[512];
    __shared__ unsigned int st[MAXB];
    int t = threadIdx.x;
    int b = blockIdx.x;
    int base = b * MAXB;
    int cnt = bcursor[b * CPAD];
    if (t < 512) lh[t] = 0;
    __syncthreads();
    for (int i = t; i < cnt; i += 1024)
        atomicAdd(&lh[staged[base + i] >> 17], 1);
    __syncthreads();
    // single-wave scan over 512 dst bins (8 bins/lane)
    if (t < 64) {
        int hvv[8];
        *(int4*)&hvv[0] = *(const int4*)&lh[t * 8];
        *(int4*)&hvv[4] = *(const int4*)&lh[t * 8 + 4];
        int ex[8]; int p = 0;
#pragma unroll
        for (int q = 0; q < 8; ++q) { ex[q] = p; p += hvv[q]; }
        int lsum = p, sc = p;
#pragma unroll
        for (int m = 1; m < 64; m <<= 1) {
            int u = __shfl_up(sc, m);
            if (t >= m) sc += u;
        }
        int lbase = sc - lsum;
#pragma unroll
        for (int q = 0; q < 8; ++q) {
            lofs2[t * 8 + q] = lbase + ex[q];
            lcur2[t * 8 + q] = lbase + ex[q];
        }
    }
    __syncthreads();
    if (t < 512) {
        int d = (b << BSH) + t;
        if (d < n) {
            offs[d] = base + lofs2[t];
            dcnt[d] = lh[t];
        }
    }
    for (int i = t; i < cnt; i += 1024) {
        unsigned int v = staged[base + i];
        int p = atomicAdd(&lcur2[v >> 17], 1);
        st[p] = v;
    }
    __syncthreads();
    for (int i = t; i < cnt; i += 1024)
        grouped[base + i] = st[i];
}

// One wave per dst. R18 layout: w-phase lanes = 16 sub x 4 head (unchanged);
// fma-phase lanes = 8 eslot x 8 ch-group. Per 16-edge chunk: 2x dwordx4 row
// loads, 2 bpermute (src idx), 2 LDS w reads, 16 shift/and + 16 fma.
// acc transposed back to lane=channel via intra-wave LDS float4 round-trip.
__global__ __launch_bounds__(256) void k_agg1(
        const int* __restrict__ offs, const int* __restrict__ dcnt,
        const unsigned int* __restrict__ grouped,
        const unsigned short* __restrict__ h1b, const float* __restrict__ as1,
        const float* __restrict__ ad1, const float* __restrict__ b1,
        const float* __restrict__ W2,
        const float* __restrict__ att_s2, const float* __restrict__ att_d2,
        float4* __restrict__ pack, int n) {
    __shared__ float wlds[4][64];
    const int lane = threadIdx.x & 63;
    const int wid = threadIdx.x >> 6;
    const int d = blockIdx.x * 4 + wid;
    if (d >= n) return;
    const int c = lane;            // epilogue channel
    const int h = lane >> 4;       // w-phase head
    const int sub = lane & 15;     // w-phase edge slot
    const int eslot = lane >> 3;   // fma-phase edge slot (0..7)
    const int cg = lane & 7;       // fma-phase channel group (8 ch each)
    const int hh2 = cg >> 1;       // head of my channel group
    const int off0 = offs[d];
    const int total = dcnt[d];                  // real edges only
    const float adh = ad1[d * 4 + h];
    const float wselfv = lrexp(as1[d * 4 + h] + adh);

    float4 accA = make_float4(0.f, 0.f, 0.f, 0.f);   // channels cg*8+0..3
    float4 accB = make_float4(0.f, 0.f, 0.f, 0.f);   // channels cg*8+4..7
    float wsum = 0.f;              // per (sub,h); self added at end

    // pipeline prologue: chunk 0 resolved (s,a); chunk 1 grouped in flight
    int s_cur = d; float a_cur = 0.f;
    if (sub < total) {
        s_cur = (int)(grouped[off0 + sub] & SRC_MASK);
        a_cur = as1[s_cur * 4 + h];
    }
    unsigned int v_n1 = 0;
    if (16 + sub < total) v_n1 = grouped[off0 + 16 + sub];

    for (int base = 0; base < total; base += 16) {
        // issue chunk k+2's grouped load
        int e2 = base + 32 + sub;
        unsigned int v_n2 = 0;
        if (e2 < total) v_n2 = grouped[off0 + e2];
        // resolve chunk k+1's (s, as1) BEFORE this chunk's fma work
        int s_n = d; float a_n = 0.f;
        if (base + 16 + sub < total) {
            s_n = (int)(v_n1 & SRC_MASK);
            a_n = as1[s_n * 4 + h];
        }
        float w = (base + sub < total) ? lrexp(a_cur + adh) : 0.f;
        wsum += w;
        wlds[wid][sub * 4 + h] = w;     // intra-wave, DS in-order: no barrier
        // src of edges base+eslot, base+8+eslot (pad edges: s_cur=d, w=0)
        int sA = __shfl(s_cur, eslot);
        int sB = __shfl(s_cur, 8 + eslot);
        // one 16B row-slice per lane per 8 edges (wave = 8 full h1 rows)
        uint4 hA = *(const uint4*)&h1b[(size_t)sA * 64 + cg * 8];
        uint4 hB = *(const uint4*)&h1b[(size_t)sB * 64 + cg * 8];
        float wA = wlds[wid][eslot * 4 + hh2];          // 2-way broadcast
        float wB = wlds[wid][(8 + eslot) * 4 + hh2];
        accA.x += wA * lo_bf(hA.x); accA.y += wA * hi_bf(hA.x);
        accA.z += wA * lo_bf(hA.y); accA.w += wA * hi_bf(hA.y);
        accB.x += wA * lo_bf(hA.z); accB.y += wA * hi_bf(hA.z);
        accB.z += wA * lo_bf(hA.w); accB.w += wA * hi_bf(hA.w);
        accA.x += wB * lo_bf(hB.x); accA.y += wB * hi_bf(hB.x);
        accA.z += wB * lo_bf(hB.y); accA.w += wB * hi_bf(hB.y);
        accB.x += wB * lo_bf(hB.z); accB.y += wB * hi_bf(hB.z);
        accB.z += wB * lo_bf(hB.w); accB.w += wB * hi_bf(hB.w);
        s_cur = s_n; a_cur = a_n; v_n1 = v_n2;
    }
    // reduce acc over the 8 eslot replicas (xor 8,16,32)
#pragma unroll
    for (int m = 8; m <= 32; m <<= 1) {
        accA.x += __shfl_xor(accA.x, m); accA.y += __shfl_xor(accA.y, m);
        accA.z += __shfl_xor(accA.z, m); accA.w += __shfl_xor(accA.w, m);
        accB.x += __shfl_xor(accB.x, m); accB.y += __shfl_xor(accB.y, m);
        accB.z += __shfl_xor(accB.z, m); accB.w += __shfl_xor(accB.w, m);
    }
    // transpose to lane=channel via LDS (8 lanes write, all read; intra-wave)
    if (eslot == 0) {
        *(float4*)&wlds[wid][cg * 8]     = accA;
        *(float4*)&wlds[wid][cg * 8 + 4] = accB;
    }
    float acc = wlds[wid][c] + wselfv * bf2f(h1b[(size_t)d * 64 + c]);
    // my 16-lane group is exactly my head -> xor-reduce within group
    wsum += __shfl_xor(wsum, 1);
    wsum += __shfl_xor(wsum, 2);
    wsum += __shfl_xor(wsum, 4);
    wsum += __shfl_xor(wsum, 8);
    wsum += wselfv;                // self counted exactly once
    float o1 = acc / (wsum + 1e-16f) + b1[c];
    // ---- fused node2: o=elu(o1); h2 = o @ W2 (wave-wide dot) ----
    float o = o1 > 0.f ? o1 : (__expf(o1) - 1.f);
    float2 wv = ((const float2*)W2)[c];
    float p0 = o * wv.x, p1 = o * wv.y;
#pragma unroll
    for (int m = 1; m < 64; m <<= 1) {
        p0 += __shfl_xor(p0, m);
        p1 += __shfl_xor(p1, m);
    }
    if (lane == 0) {
        pack[d] = make_float4(p0, p1,
                              p0 * att_s2[0] + p1 * att_s2[1],
                              p0 * att_d2[0] + p1 * att_d2[1]);
    }
}

// 16 lanes per dst node; one 16B pack gather per edge (h0,h1,as2,ad2).
// pack is 1.6 MB -> L2-resident. Self on sub==0 lane only (counted once).
__global__ __launch_bounds__(256) void k_agg2(
        const int* __restrict__ offs, const int* __restrict__ dcnt,
        const unsigned int* __restrict__ grouped,
        const float4* __restrict__ pack, const float* __restrict__ b2,
        float* __restrict__ out, int n) {
    int t = threadIdx.x;
    int g = blockIdx.x * 16 + (t >> 4);
    int sub = t & 15;
    if (g >= n) return;
    int off0 = offs[g];
    int total = dcnt[g];
    float4 pg = pack[g];
    float ad = pg.w;
    float a0 = 0.f, a1 = 0.f, ws = 0.f;
    if (sub == 0) {
        float w = lrexp(pg.z + ad);
        a0 = w * pg.x; a1 = w * pg.y; ws = w;
    }
    for (int e = sub; e < total; e += 16) {
        int s = (int)(grouped[off0 + e] & SRC_MASK);
        float4 ps = pack[s];
        float w = lrexp(ps.z + ad);
        a0 += w * ps.x; a1 += w * ps.y; ws += w;
    }
#pragma unroll
    for (int m = 1; m < 16; m <<= 1) {
        a0 += __shfl_xor(a0, m);
        a1 += __shfl_xor(a1, m);
        ws += __shfl_xor(ws, m);
    }
    if (sub == 0) {
        float inv = 1.f / (ws + 1e-16f);
        out[(size_t)g * 2 + 0] = a0 * inv + b2[0];
        out[(size_t)g * 2 + 1] = a1 * inv + b2[1];
    }
}

extern "C" void kernel_launch(void* const* d_in, const int* in_sizes, int n_in,
                              void* d_out, int out_size, void* d_ws, size_t ws_size,
                              hipStream_t stream) {
    const float* x    = (const float*)d_in[0];
    const int*   ei   = (const int*)d_in[1];
    const float* W1   = (const float*)d_in[2];
    const float* as1w = (const float*)d_in[3];
    const float* ad1w = (const float*)d_in[4];
    const float* b1   = (const float*)d_in[5];
    const float* W2   = (const float*)d_in[6];
    const float* as2w = (const float*)d_in[7];
    const float* ad2w = (const float*)d_in[8];
    const float* b2   = (const float*)d_in[9];
    const int n = in_sizes[0] / 128;
    const int E = in_sizes[1] / 2;
    float* out = (float*)d_out;

    char* ws = (char*)d_ws;
    size_t off = 0;
    auto alloc = [&](size_t bytes) {
        void* p = ws + off;
        off = (off + bytes + 255) & ~(size_t)255;
        return p;
    };
    unsigned short* h1b = (unsigned short*)alloc((size_t)n * 64 * 2);
    float*  as1    = (float*)alloc((size_t)n * 4 * 4);
    float*  ad1    = (float*)alloc((size_t)n * 4 * 4);
    float4* pack   = (float4*)alloc((size_t)n * 16);
    int*    offs   = (int*)alloc((size_t)n * 4);
    int*    dcnt   = (int*)alloc((size_t)n * 4);
    int*    bcursor= (int*)alloc(NB * CPAD * 4);
    unsigned short* Wt = (unsigned short*)alloc(64 * 128 * 2);
    unsigned int* staged  = (unsigned int*)alloc((size_t)NB * MAXB * 4);
    unsigned int* grouped = (unsigned int*)alloc((size_t)NB * MAXB * 4);

    hipMemsetAsync(bcursor, 0, NB * CPAD * 4, stream);

    const int nG = (n + 63) / 64;
    const int nB = (E + KC_CHUNK - 1) / KC_CHUNK;
    const int nbk = (n + 511) >> 9;          // actual buckets (196 @ n=100k)
    k_prep<<<1, 1024, 0, stream>>>(W1, Wt);
    k_gemm<<<nG, 256, 0, stream>>>(x, Wt, as1w, ad1w, h1b, as1, ad1, n);
    k_bin<<<nB, 256, 0, stream>>>(ei, ei + E, bcursor, staged, E);
    kD_group<<<nbk, 1024, 0, stream>>>(staged, bcursor, grouped, offs, dcnt, n);
    k_agg1<<<(n + 3) / 4, 256, 0, stream>>>(offs, dcnt, grouped, h1b, as1, ad1,
                                            b1, W2, as2w, ad2w, pack, n);
    k_agg2<<<(n + 15) / 16, 256, 0, stream>>>(offs, dcnt, grouped, pack, b2, out, n);
}

// Round 8
// 207.872 us; speedup vs baseline: 1.1152x; 1.1152x over previous
//
#include <hip/hip_runtime.h>
#include <math.h>

// ---------------------------------------------------------------------------
// GAT 2-layer forward — memset + 5 kernels.
//   memset    : bcursor = 0 (32 KB, PADDED: 1 line / bucket)
//   k_prep    : Wt[64][128] = bf16(W1^T), 16 KB, one small block.
//   k_front   : R19 re-fusion of MFMA-GEMM + edge-bin (one launch so the two
//               independent phases overlap; R1 vs R6 showed splitting costs
//               ~14us of serialization). Blocks [0,nG): h1b = bf16(x@W1) via
//               MFMA 16x16x32_bf16, 64-row tiles (R16 structure). Blocks
//               [nG,nG+nB): bin edges by bucket (dst>>9) into BUCKET-STRIDED
//               staged[] (b*MAXB + atomic pos), LDS-reordered, KC_CHUNK=2048.
//               bcursor PADDED 128B/bucket (R17) — R5's fused run was 86us
//               with 200k atomics on 8 cache lines; R6 proved padding fixes
//               the bin phase. This round tests that attribution.
//   kD_group  : per bucket: local 512-dst hist+scan -> offs[d]/dcnt[d];
//               LDS-position edges -> grouped[] (dst-sorted), coalesced
//               flush. 1024 thr, single-wave scan.
//   k_agg1    : one wave/dst, 16 slots x 4 heads — R6 EXACT (56.6us best;
//               R7's 2D relayout regressed to 65.9: fewer instrs but a
//               serialized shfl->LDS->FMA chain + bank conflicts beat the 16
//               independent 2B gathers). Slot weights broadcast via per-wave
//               LDS line + 4x ds_read_b128; DEPTH-2 grouped prefetch; wsum
//               per-lane + 4 shfl_xor. Fused node2 epilogue.
//   k_agg2    : out[d,:] via single 16B pack gather per edge; self on sub==0.
// R4 lesson: random 4B scatter to >L2 buffer costs 64B/line HBM writes.
// segment_max skipped (exp/sum identical post-normalization). h1 as bf16.
// ---------------------------------------------------------------------------

#define NB 256          // bucket array size
#define BSH 9           // bucket shift (512 dst/bucket)
#define CPAD 32         // bcursor stride in ints (128 B = 1 L2 line)
#define SRC_MASK 0x1FFFF
#define KC_CHUNK 2048
#define KC_PT 8         // edges per thread in bin phase (256 threads)
#define MAXB 9216       // capacity/bucket (mean 8163, sigma ~90 -> +11 sigma)

typedef short v8s __attribute__((ext_vector_type(8)));
typedef float v4f __attribute__((ext_vector_type(4)));

static __device__ __forceinline__ unsigned short f2bf(float f) {
    union { float f; unsigned int u; } v; v.f = f;
    unsigned int r = (v.u + 0x7fffu + ((v.u >> 16) & 1u)) >> 16;
    return (unsigned short)r;
}
static __device__ __forceinline__ float bf2f(unsigned short s) {
    union { unsigned int u; float f; } v; v.u = ((unsigned int)s) << 16;
    return v.f;
}
static __device__ __forceinline__ float lrexp(float raw) {
    return __expf(raw > 0.f ? raw : 0.2f * raw);
}

// ---- prelude: Wt[c][k] = bf16(W[k][c]) ----
__global__ __launch_bounds__(1024) void k_prep(const float* __restrict__ W,
                                               unsigned short* __restrict__ Wt) {
    int t = threadIdx.x;
    for (int i = t; i < 8192; i += 1024) {
        int c = i >> 7, k = i & 127;
        Wt[i] = f2bf(W[k * 64 + c]);
    }
}

// ---- fused MFMA-GEMM (blocks < nG) + edge-bin (blocks >= nG) ----
__global__ __launch_bounds__(256, 4) void k_front(
        const float* __restrict__ x, const unsigned short* __restrict__ Wt,
        const float* __restrict__ att_s, const float* __restrict__ att_d,
        unsigned short* __restrict__ h1b, float* __restrict__ as1,
        float* __restrict__ ad1,
        const int* __restrict__ esrc, const int* __restrict__ edst,
        int* __restrict__ bcursor, unsigned int* __restrict__ staged,
        int nG, int E, int n) {
    __shared__ __align__(16) char smem[33280];
    const int t = threadIdx.x;

    if (blockIdx.x < nG) {
        // ============ GEMM phase: 64 rows x 64 cols, K=128, 4 waves ========
        float* Cs = (float*)(smem + 16384);        // 64 x 64, stride 65
        const int row0 = blockIdx.x * 64;
        const int L = t & 63, wv = t >> 6;

        // B-fragments: issue early (global, L2-broadcast), hide under staging
        v8s bfrag[4][4];
        const v8s* Wtv = (const v8s*)Wt;
        const int bci = ((L & 15) << 4) + (L >> 4);
#pragma unroll
        for (int ct = 0; ct < 4; ++ct)
#pragma unroll
            for (int kb = 0; kb < 4; ++kb)
                bfrag[ct][kb] = Wtv[bci + (ct << 8) + (kb << 2)];

        // stage x tile as bf16, swizzled: byte = r*256 + ((k4*8)^((r&7)<<4))
        for (int i = t; i < 2048; i += 256) {
            int r = i >> 5, k4 = i & 31;
            float4 v = make_float4(0.f, 0.f, 0.f, 0.f);
            if (row0 + r < n) v = ((const float4*)x)[(size_t)(row0 + r) * 32 + k4];
            ushort4 u;
            u.x = f2bf(v.x); u.y = f2bf(v.y); u.z = f2bf(v.z); u.w = f2bf(v.w);
            int byte = r * 256 + ((k4 * 8) ^ ((r & 7) << 4));
            *(ushort4*)(smem + byte) = u;
        }
        __syncthreads();

        v4f acc[4] = {{0.f,0.f,0.f,0.f}, {0.f,0.f,0.f,0.f},
                      {0.f,0.f,0.f,0.f}, {0.f,0.f,0.f,0.f}};
        const int row = (wv << 4) + (L & 15);
#pragma unroll
        for (int kb = 0; kb < 4; ++kb) {
            int byte = row * 256 + (((kb << 6) + ((L >> 4) << 4)) ^ ((row & 7) << 4));
            v8s afrag = *(const v8s*)(smem + byte);
#pragma unroll
            for (int ct = 0; ct < 4; ++ct)
                acc[ct] = __builtin_amdgcn_mfma_f32_16x16x32_bf16(
                    afrag, bfrag[ct][kb], acc[ct], 0, 0, 0);
        }
        // C -> LDS (stride 65)
#pragma unroll
        for (int ct = 0; ct < 4; ++ct) {
            int col = (ct << 4) + (L & 15);
            int rbase = (wv << 4) + ((L >> 4) << 2);
#pragma unroll
            for (int q = 0; q < 4; ++q)
                Cs[(rbase + q) * 65 + col] = acc[ct][q];
        }
        __syncthreads();
        // h1b: t -> (row = t>>2, q = t&3): 16 cols, coalesced ushort4 x4
        {
            int row = t >> 2, q = t & 3;
            const float* cp = &Cs[row * 65 + q * 16];
            int r = row0 + row;
            if (r < n) {
                ushort4 u0, u1, u2, u3;
                u0.x = f2bf(cp[0]);  u0.y = f2bf(cp[1]);
                u0.z = f2bf(cp[2]);  u0.w = f2bf(cp[3]);
                u1.x = f2bf(cp[4]);  u1.y = f2bf(cp[5]);
                u1.z = f2bf(cp[6]);  u1.w = f2bf(cp[7]);
                u2.x = f2bf(cp[8]);  u2.y = f2bf(cp[9]);
                u2.z = f2bf(cp[10]); u2.w = f2bf(cp[11]);
                u3.x = f2bf(cp[12]); u3.y = f2bf(cp[13]);
                u3.z = f2bf(cp[14]); u3.w = f2bf(cp[15]);
                ushort4* hp = (ushort4*)h1b + ((size_t)r * 16 + q * 4);
                hp[0] = u0; hp[1] = u1; hp[2] = u2; hp[3] = u3;
            }
        }
        // as1/ad1: t -> (row = t&63, h = t>>6); h wave-uniform -> s_load att
        {
            int row = t & 63, h = t >> 6;
            const float* cp = &Cs[row * 65 + h * 16];
            const float* asp = att_s + (h << 4);
            const float* adp = att_d + (h << 4);
            float ps = 0.f, pd = 0.f;
#pragma unroll
            for (int j = 0; j < 16; ++j) {
                ps += cp[j] * asp[j];
                pd += cp[j] * adp[j];
            }
            int r = row0 + row;
            if (r < n) {
                as1[r * 4 + h] = ps;
                ad1[r * 4 + h] = pd;
            }
        }
    } else {
        // ================= BIN phase (256 threads, 2048 edges) ============
        unsigned int* pairs = (unsigned int*)smem;               // 8192 B
        unsigned char* binOf = (unsigned char*)(smem + 8192);    // 2048 B
        int* hh    = (int*)(smem + 10240);
        int* lofs  = (int*)(smem + 11264);
        int* lcur  = (int*)(smem + 12288);
        int* gbase = (int*)(smem + 13312);
        int base = (blockIdx.x - nG) * KC_CHUNK;
        int cnt = E - base; if (cnt > KC_CHUNK) cnt = KC_CHUNK;
        hh[t] = 0; __syncthreads();
        unsigned int myV[KC_PT]; int myBin[KC_PT];
#pragma unroll
        for (int k = 0; k < KC_PT; ++k) {
            int li = k * 256 + t;
            myBin[k] = -1;
            if (li < cnt) {
                int gi = base + li;
                int s = esrc[gi], d = edst[gi];
                int bin = d >> BSH;
                myV[k] = ((unsigned int)(d & ((1 << BSH) - 1)) << 17) | (unsigned int)s;
                myBin[k] = bin;
                atomicAdd(&hh[bin], 1);
            }
        }
        __syncthreads();
        // single-wave scan over 256 bins (4 bins/lane)
        if (t < 64) {
            int hvv[4];
            *(int4*)hvv = *(const int4*)&hh[t * 4];
            int ex[4]; int p = 0;
#pragma unroll
            for (int q = 0; q < 4; ++q) { ex[q] = p; p += hvv[q]; }
            int lsum = p, sc = p;
#pragma unroll
            for (int m = 1; m < 64; m <<= 1) {
                int u = __shfl_up(sc, m);
                if (t >= m) sc += u;
            }
            int lbase = sc - lsum;
#pragma unroll
            for (int q = 0; q < 4; ++q) {
                int b = t * 4 + q;
                lofs[b] = lbase + ex[q];
                lcur[b] = lbase + ex[q];
                if (hvv[q]) gbase[b] = b * MAXB + atomicAdd(&bcursor[b * CPAD], hvv[q]);
            }
        }
        __syncthreads();
#pragma unroll
        for (int k = 0; k < KC_PT; ++k) {
            if (myBin[k] >= 0) {
                int p = atomicAdd(&lcur[myBin[k]], 1);
                pairs[p] = myV[k];
                binOf[p] = (unsigned char)myBin[k];
            }
        }
        __syncthreads();
        for (int i = t; i < cnt; i += 256) {
            int b = binOf[i];
            staged[gbase[b] + (i - lofs[b])] = pairs[i];
        }
    }
}

// Per bucket: local hist over 512 dst -> scan -> offs[d] (strided) + dcnt[d];
// LDS-position edges dst-sorted -> grouped[] coalesced flush.
__global__ __launch_bounds__(1024) void kD_group(const unsigned int* __restrict__ staged,
                                                 const int* __restrict__ bcursor,
                                                 unsigned int* __restrict__ grouped,
                                                 int* __restrict__ offs,
                                                 int* __restrict__ dcnt, int n) {
    __shared__ int lh[512], lofs2[512], lcur2[512];
    __shared__ unsigned int st[MAXB];
    int t = threadIdx.x;
    int b = blockIdx.x;
    int base = b * MAXB;
    int cnt = bcursor[b * CPAD];
    if (t < 512) lh[t] = 0;
    __syncthreads();
    for (int i = t; i < cnt; i += 1024)
        atomicAdd(&lh[staged[base + i] >> 17], 1);
    __syncthreads();
    // single-wave scan over 512 dst bins (8 bins/lane)
    if (t < 64) {
        int hvv[8];
        *(int4*)&hvv[0] = *(const int4*)&lh[t * 8];
        *(int4*)&hvv[4] = *(const int4*)&lh[t * 8 + 4];
        int ex[8]; int p = 0;
#pragma unroll
        for (int q = 0; q < 8; ++q) { ex[q] = p; p += hvv[q]; }
        int lsum = p, sc = p;
#pragma unroll
        for (int m = 1; m < 64; m <<= 1) {
            int u = __shfl_up(sc, m);
            if (t >= m) sc += u;
        }
        int lbase = sc - lsum;
#pragma unroll
        for (int q = 0; q < 8; ++q) {
            lofs2[t * 8 + q] = lbase + ex[q];
            lcur2[t * 8 + q] = lbase + ex[q];
        }
    }
    __syncthreads();
    if (t < 512) {
        int d = (b << BSH) + t;
        if (d < n) {
            offs[d] = base + lofs2[t];
            dcnt[d] = lh[t];
        }
    }
    for (int i = t; i < cnt; i += 1024) {
        unsigned int v = staged[base + i];
        int p = atomicAdd(&lcur2[v >> 17], 1);
        st[p] = v;
    }
    __syncthreads();
    for (int i = t; i < cnt; i += 1024)
        grouped[base + i] = st[i];
}

// One wave per dst. 64 lanes = 16 slots x 4 heads. Self-loop hoisted.
// DEPTH-2 pipeline over chunks. Slot weights broadcast via per-wave LDS line
// + 4x ds_read_b128; wsum per-lane accumulated, 4x shfl_xor at end. (R6 exact)
__global__ __launch_bounds__(256) void k_agg1(
        const int* __restrict__ offs, const int* __restrict__ dcnt,
        const unsigned int* __restrict__ grouped,
        const unsigned short* __restrict__ h1b, const float* __restrict__ as1,
        const float* __restrict__ ad1, const float* __restrict__ b1,
        const float* __restrict__ W2,
        const float* __restrict__ att_s2, const float* __restrict__ att_d2,
        float4* __restrict__ pack, int n) {
    __shared__ float wlds[4][64];
    const int lane = threadIdx.x & 63;
    const int wid = threadIdx.x >> 6;
    const int d = blockIdx.x * 4 + wid;
    if (d >= n) return;
    const int c = lane;            // output channel
    const int h = lane >> 4;       // head of my channel == weight head
    const int sub = lane & 15;     // edge slot in chunk
    const int off0 = offs[d];
    const int total = dcnt[d];                  // real edges only
    const float adh = ad1[d * 4 + h];
    const float wselfv = lrexp(as1[d * 4 + h] + adh);

    // self-loop contribution to acc (per-channel, never reduced)
    float acc = wselfv * bf2f(h1b[(size_t)d * 64 + c]);
    float wsum = 0.f;              // self added once at the end

    // pipeline prologue: chunk 0 resolved (s,a); chunk 1 grouped in flight
    int s_cur = d; float a_cur = 0.f;
    if (sub < total) {
        unsigned int v = grouped[off0 + sub];
        s_cur = (int)(v & SRC_MASK);
        a_cur = as1[s_cur * 4 + h];
    }
    unsigned int v_n1 = 0;
    if (16 + sub < total) v_n1 = grouped[off0 + 16 + sub];

    for (int base = 0; base < total; base += 16) {
        // issue chunk k+2's grouped load
        int e2 = base + 32 + sub;
        unsigned int v_n2 = 0;
        if (e2 < total) v_n2 = grouped[off0 + e2];
        // resolve chunk k+1's (s, as1) BEFORE this chunk's j-loop
        int s_n = d; float a_n = 0.f;
        if (base + 16 + sub < total) {
            s_n = (int)(v_n1 & SRC_MASK);
            a_n = as1[s_n * 4 + h];
        }
        float w = (base + sub < total) ? lrexp(a_cur + adh) : 0.f;
        wsum += w;                      // per-lane slot accumulation
        wlds[wid][lane] = w;            // intra-wave, DS in-order: no barrier
        int s = s_cur;
        unsigned short hv_[16];
#pragma unroll
        for (int j = 0; j < 16; ++j) {
            int sj = __builtin_amdgcn_readlane(s, j);   // wave-uniform -> SGPR
            hv_[j] = h1b[(size_t)sj * 64 + c];          // 16 loads in flight
        }
        const float* wvp = &wlds[wid][h * 16];
        float4 wa = *(const float4*)(wvp);
        float4 wb = *(const float4*)(wvp + 4);
        float4 wc = *(const float4*)(wvp + 8);
        float4 wd = *(const float4*)(wvp + 12);
        acc += wa.x * bf2f(hv_[0]);  acc += wa.y * bf2f(hv_[1]);
        acc += wa.z * bf2f(hv_[2]);  acc += wa.w * bf2f(hv_[3]);
        acc += wb.x * bf2f(hv_[4]);  acc += wb.y * bf2f(hv_[5]);
        acc += wb.z * bf2f(hv_[6]);  acc += wb.w * bf2f(hv_[7]);
        acc += wc.x * bf2f(hv_[8]);  acc += wc.y * bf2f(hv_[9]);
        acc += wc.z * bf2f(hv_[10]); acc += wc.w * bf2f(hv_[11]);
        acc += wd.x * bf2f(hv_[12]); acc += wd.y * bf2f(hv_[13]);
        acc += wd.z * bf2f(hv_[14]); acc += wd.w * bf2f(hv_[15]);
        s_cur = s_n; a_cur = a_n; v_n1 = v_n2;
    }
    // my 16-lane group is exactly my head -> xor-reduce within group
    wsum += __shfl_xor(wsum, 1);
    wsum += __shfl_xor(wsum, 2);
    wsum += __shfl_xor(wsum, 4);
    wsum += __shfl_xor(wsum, 8);
    wsum += wselfv;                // self counted exactly once
    float o1 = acc / (wsum + 1e-16f) + b1[c];
    // ---- fused node2: o=elu(o1); h2 = o @ W2 (wave-wide dot) ----
    float o = o1 > 0.f ? o1 : (__expf(o1) - 1.f);
    float2 wv = ((const float2*)W2)[c];
    float p0 = o * wv.x, p1 = o * wv.y;
#pragma unroll
    for (int m = 1; m < 64; m <<= 1) {
        p0 += __shfl_xor(p0, m);
        p1 += __shfl_xor(p1, m);
    }
    if (lane == 0) {
        pack[d] = make_float4(p0, p1,
                              p0 * att_s2[0] + p1 * att_s2[1],
                              p0 * att_d2[0] + p1 * att_d2[1]);
    }
}

// 16 lanes per dst node; one 16B pack gather per edge (h0,h1,as2,ad2).
// pack is 1.6 MB -> L2-resident. Self on sub==0 lane only (counted once).
__global__ __launch_bounds__(256) void k_agg2(
        const int* __restrict__ offs, const int* __restrict__ dcnt,
        const unsigned int* __restrict__ grouped,
        const float4* __restrict__ pack, const float* __restrict__ b2,
        float* __restrict__ out, int n) {
    int t = threadIdx.x;
    int g = blockIdx.x * 16 + (t >> 4);
    int sub = t & 15;
    if (g >= n) return;
    int off0 = offs[g];
    int total = dcnt[g];
    float4 pg = pack[g];
    float ad = pg.w;
    float a0 = 0.f, a1 = 0.f, ws = 0.f;
    if (sub == 0) {
        float w = lrexp(pg.z + ad);
        a0 = w * pg.x; a1 = w * pg.y; ws = w;
    }
    for (int e = sub; e < total; e += 16) {
        int s = (int)(grouped[off0 + e] & SRC_MASK);
        float4 ps = pack[s];
        float w = lrexp(ps.z + ad);
        a0 += w * ps.x; a1 += w * ps.y; ws += w;
    }
#pragma unroll
    for (int m = 1; m < 16; m <<= 1) {
        a0 += __shfl_xor(a0, m);
        a1 += __shfl_xor(a1, m);
        ws += __shfl_xor(ws, m);
    }
    if (sub == 0) {
        float inv = 1.f / (ws + 1e-16f);
        out[(size_t)g * 2 + 0] = a0 * inv + b2[0];
        out[(size_t)g * 2 + 1] = a1 * inv + b2[1];
    }
}

extern "C" void kernel_launch(void* const* d_in, const int* in_sizes, int n_in,
                              void* d_out, int out_size, void* d_ws, size_t ws_size,
                              hipStream_t stream) {
    const float* x    = (const float*)d_in[0];
    const int*   ei   = (const int*)d_in[1];
    const float* W1   = (const float*)d_in[2];
    const float* as1w = (const float*)d_in[3];
    const float* ad1w = (const float*)d_in[4];
    const float* b1   = (const float*)d_in[5];
    const float* W2   = (const float*)d_in[6];
    const float* as2w = (const float*)d_in[7];
    const float* ad2w = (const float*)d_in[8];
    const float* b2   = (const float*)d_in[9];
    const int n = in_sizes[0] / 128;
    const int E = in_sizes[1] / 2;
    float* out = (float*)d_out;

    char* ws = (char*)d_ws;
    size_t off = 0;
    auto alloc = [&](size_t bytes) {
        void* p = ws + off;
        off = (off + bytes + 255) & ~(size_t)255;
        return p;
    };
    unsigned short* h1b = (unsigned short*)alloc((size_t)n * 64 * 2);
    float*  as1    = (float*)alloc((size_t)n * 4 * 4);
    float*  ad1    = (float*)alloc((size_t)n * 4 * 4);
    float4* pack   = (float4*)alloc((size_t)n * 16);
    int*    offs   = (int*)alloc((size_t)n * 4);
    int*    dcnt   = (int*)alloc((size_t)n * 4);
    int*    bcursor= (int*)alloc(NB * CPAD * 4);
    unsigned short* Wt = (unsigned short*)alloc(64 * 128 * 2);
    unsigned int* staged  = (unsigned int*)alloc((size_t)NB * MAXB * 4);
    unsigned int* grouped = (unsigned int*)alloc((size_t)NB * MAXB * 4);

    hipMemsetAsync(bcursor, 0, NB * CPAD * 4, stream);

    const int nG = (n + 63) / 64;
    const int nB = (E + KC_CHUNK - 1) / KC_CHUNK;
    const int nbk = (n + 511) >> 9;          // actual buckets (196 @ n=100k)
    k_prep<<<1, 1024, 0, stream>>>(W1, Wt);
    k_front<<<nG + nB, 256, 0, stream>>>(x, Wt, as1w, ad1w, h1b, as1, ad1,
                                         ei, ei + E, bcursor, staged, nG, E, n);
    kD_group<<<nbk, 1024, 0, stream>>>(staged, bcursor, grouped, offs, dcnt, n);
    k_agg1<<<(n + 3) / 4, 256, 0, stream>>>(offs, dcnt, grouped, h1b, as1, ad1,
                                            b1, W2, as2w, ad2w, pack, n);
    k_agg2<<<(n + 15) / 16, 256, 0, stream>>>(offs, dcnt, grouped, pack, b2, out, n);
}